// Round 4
// baseline (74.727 us; speedup 1.0000x reference)
//
#include <hip/hip_runtime.h>
#include <stdint.h>

#define IN_F   512
#define N_CTR  2048
#define BATCH  16384

#define BM 128
#define BN 128
#define BK 64
#define NKT (IN_F / BK)   // 8

using bf16x8  = __attribute__((ext_vector_type(8))) short;
using f32x4   = __attribute__((ext_vector_type(4))) float;
using ushort8 = __attribute__((ext_vector_type(8))) unsigned short;

typedef const __attribute__((address_space(1))) void* gptr_t;
typedef __attribute__((address_space(3))) void* lptr_t;

static __device__ __forceinline__ unsigned short f2bf(float f) {
    uint32_t u = __builtin_bit_cast(uint32_t, f);
    uint32_t r = u + 0x7fffu + ((u >> 16) & 1u);   // RNE
    return (unsigned short)(r >> 16);
}

// Merged converter: one wave per row across BOTH x and centers.
// Converts f32 row -> bf16 row, emits exact-f32 sum of squares.
__global__ void convert_all(const float* __restrict__ x,
                            const float* __restrict__ c,
                            unsigned short* __restrict__ xb,
                            unsigned short* __restrict__ cb,
                            float* __restrict__ xsq,
                            float* __restrict__ csq) {
    const int wave = threadIdx.x >> 6;                 // 0..3
    const int lane = threadIdx.x & 63;
    const int row  = blockIdx.x * 4 + wave;            // global row id

    const float* src;
    unsigned short* dst;
    float* sq;
    int r;
    if (row < BATCH) { src = x; dst = xb; sq = xsq; r = row; }
    else             { src = c; dst = cb; sq = csq; r = row - BATCH; }

    const float* rp = src + (size_t)r * IN_F + lane * 8;
    float4 a = *reinterpret_cast<const float4*>(rp);
    float4 b = *reinterpret_cast<const float4*>(rp + 4);
    float ss = a.x*a.x + a.y*a.y + a.z*a.z + a.w*a.w
             + b.x*b.x + b.y*b.y + b.z*b.z + b.w*b.w;
    ushort8 o;
    o[0]=f2bf(a.x); o[1]=f2bf(a.y); o[2]=f2bf(a.z); o[3]=f2bf(a.w);
    o[4]=f2bf(b.x); o[5]=f2bf(b.y); o[6]=f2bf(b.z); o[7]=f2bf(b.w);
    *reinterpret_cast<ushort8*>(dst + (size_t)r * IN_F + lane * 8) = o;
    #pragma unroll
    for (int off = 32; off > 0; off >>= 1) ss += __shfl_down(ss, off);
    if (lane == 0) sq[r] = ss;
}

// 128x128 tile bf16 MFMA GEMM with T4 counted-vmcnt double-buffer pipeline:
// stage(t+1) -> s_waitcnt vmcnt(8) (tile t landed, t+1's 8 loads stay in
// flight) -> s_barrier -> compute(t) -> s_barrier. No vmcnt(0) drain in the
// main loop. Fused RBF epilogue.
__launch_bounds__(256, 2)
__global__ void rbf_gemm(const unsigned short* __restrict__ xb,
                         const unsigned short* __restrict__ cb,
                         const float* __restrict__ xsq,
                         const float* __restrict__ csq,
                         const float* __restrict__ beta,
                         float* __restrict__ out) {
    __shared__ unsigned short As[2][BM * BK];   // 2 x 16 KB
    __shared__ unsigned short Bs[2][BN * BK];   // 2 x 16 KB

    const int tid  = threadIdx.x;
    const int wid  = tid >> 6;
    const int lane = tid & 63;
    const int wr   = wid >> 1;               // 0..1
    const int wc   = wid & 1;                // 0..1

    // T1: XCD chunked swizzle (bijective since gridDim.x % 8 == 0).
    const int nwg = gridDim.x;               // 2048
    const int bid = blockIdx.x;
    const int swz = (bid & 7) * (nwg >> 3) + (bid >> 3);

    const int ntn = N_CTR / BN;              // 16
    const int tm  = swz / ntn;
    const int tn  = swz % ntn;

    // staging geometry: per wave 4 issues per matrix; each issue = 64 lanes x 16B
    // = 8 LDS rows (row-linear dest, required by global_load_lds).
    const int srow = (wid * 4) * 8 + (lane >> 3);   // +i*8 per issue
    const int scol = (lane & 7) * 8;                // element col within row
    const unsigned short* gA0 = xb + (size_t)(tm * BM + srow) * IN_F + scol;
    const unsigned short* gB0 = cb + (size_t)(tn * BN + srow) * IN_F + scol;

    f32x4 acc[4][4] = {};

    auto stage = [&](int buf, int kt) {
        const int kbase = kt * BK;
        #pragma unroll
        for (int i = 0; i < 4; ++i) {
            const unsigned short* ga = gA0 + (size_t)(i * 8) * IN_F + kbase;
            const unsigned short* gb = gB0 + (size_t)(i * 8) * IN_F + kbase;
            __builtin_amdgcn_global_load_lds((gptr_t)ga, (lptr_t)(&As[buf][(wid * 4 + i) * 512]), 16, 0, 0);
            __builtin_amdgcn_global_load_lds((gptr_t)gb, (lptr_t)(&Bs[buf][(wid * 4 + i) * 512]), 16, 0, 0);
        }
    };

    auto compute = [&](int buf) {
        #pragma unroll
        for (int kk = 0; kk < 2; ++kk) {
            bf16x8 af[4], bfr[4];
            const int kreg = kk * 32 + (lane >> 4) * 8;
            #pragma unroll
            for (int mi = 0; mi < 4; ++mi)
                af[mi] = *reinterpret_cast<const bf16x8*>(
                    &As[buf][(wr * 64 + mi * 16 + (lane & 15)) * BK + kreg]);
            #pragma unroll
            for (int ni = 0; ni < 4; ++ni)
                bfr[ni] = *reinterpret_cast<const bf16x8*>(
                    &Bs[buf][(wc * 64 + ni * 16 + (lane & 15)) * BK + kreg]);
            #pragma unroll
            for (int mi = 0; mi < 4; ++mi)
                #pragma unroll
                for (int ni = 0; ni < 4; ++ni)
                    acc[mi][ni] = __builtin_amdgcn_mfma_f32_16x16x32_bf16(
                        af[mi], bfr[ni], acc[mi][ni], 0, 0, 0);
        }
    };

    // ---- prologue: stage tile 0 into buf 0 ----
    stage(0, 0);

    // ---- main loop: counted-vmcnt pipeline ----
    #pragma unroll
    for (int t = 0; t < NKT; ++t) {
        if (t + 1 < NKT) {
            stage((t + 1) & 1, t + 1);            // issue BEFORE the wait
            asm volatile("s_waitcnt vmcnt(8)" ::: "memory");   // tile t landed
        } else {
            asm volatile("s_waitcnt vmcnt(0)" ::: "memory");   // last tile: drain
        }
        __builtin_amdgcn_s_barrier();             // acquire: tile t visible to all
        __builtin_amdgcn_sched_barrier(0);
        compute(t & 1);                           // MFMAs force lgkmcnt on own reads
        __builtin_amdgcn_sched_barrier(0);
        if (t + 1 < NKT)
            __builtin_amdgcn_s_barrier();         // release: all readers done before
                                                  // next iter's stage overwrites
    }

    // ---- epilogue: out = exp(-beta * (xsq + csq - 2*cross)) ----
    const int row0 = tm * BM + wr * 64;
    const int col0 = tn * BN + wc * 64;
    #pragma unroll
    for (int ni = 0; ni < 4; ++ni) {
        const int col = col0 + ni * 16 + (lane & 15);
        const float bt = beta[col];
        const float cs = csq[col];
        #pragma unroll
        for (int mi = 0; mi < 4; ++mi) {
            #pragma unroll
            for (int j = 0; j < 4; ++j) {
                const int row = row0 + mi * 16 + (lane >> 4) * 4 + j;
                const float d = xsq[row] + cs - 2.0f * acc[mi][ni][j];
                out[(size_t)row * N_CTR + col] = __expf(-bt * d);
            }
        }
    }
}

// Fallback (ws too small): correct f32 path, LDS-staged x row.
__global__ void rbf_naive(const float* __restrict__ x,
                          const float* __restrict__ c,
                          const float* __restrict__ beta,
                          float* __restrict__ out) {
    __shared__ float xs[IN_F];
    const int row = blockIdx.x;
    const int col = blockIdx.y * 128 + threadIdx.x;
    for (int i = threadIdx.x; i < IN_F; i += 128)
        xs[i] = x[(size_t)row * IN_F + i];
    __syncthreads();
    const float* cp = c + (size_t)col * IN_F;
    float d = 0.f;
    #pragma unroll 4
    for (int k = 0; k < IN_F; k += 4) {
        float4 cv = *reinterpret_cast<const float4*>(cp + k);
        float t0 = xs[k + 0] - cv.x;
        float t1 = xs[k + 1] - cv.y;
        float t2 = xs[k + 2] - cv.z;
        float t3 = xs[k + 3] - cv.w;
        d += t0 * t0 + t1 * t1 + t2 * t2 + t3 * t3;
    }
    out[(size_t)row * N_CTR + col] = __expf(-beta[col] * d);
}

extern "C" void kernel_launch(void* const* d_in, const int* in_sizes, int n_in,
                              void* d_out, int out_size, void* d_ws, size_t ws_size,
                              hipStream_t stream) {
    const float* x    = (const float*)d_in[0];
    const float* c    = (const float*)d_in[1];
    const float* beta = (const float*)d_in[2];
    float* out        = (float*)d_out;

    const size_t need = (size_t)BATCH * IN_F * 2 + (size_t)N_CTR * IN_F * 2
                      + (size_t)BATCH * 4 + (size_t)N_CTR * 4;
    if (ws_size >= need) {
        unsigned short* xbuf = (unsigned short*)d_ws;
        unsigned short* cbuf = xbuf + (size_t)BATCH * IN_F;
        float* xsq = (float*)(cbuf + (size_t)N_CTR * IN_F);
        float* csq = xsq + BATCH;
        convert_all<<<(BATCH + N_CTR) / 4, 256, 0, stream>>>(x, c, xbuf, cbuf, xsq, csq);
        rbf_gemm<<<(BATCH / BM) * (N_CTR / BN), 256, 0, stream>>>(
            xbuf, cbuf, xsq, csq, beta, out);
    } else {
        rbf_naive<<<dim3(BATCH, N_CTR / 128), 128, 0, stream>>>(x, c, beta, out);
    }
}

// Round 5
// 68.344 us; speedup vs baseline: 1.0934x; 1.0934x over previous
//
#include <hip/hip_runtime.h>
#include <stdint.h>

#define IN_F   512
#define N_CTR  2048
#define BATCH  16384

#define BM 256
#define BN 256
#define BK 64
#define NT (IN_F / BK)    // 8 K-tiles

using bf16x8  = __attribute__((ext_vector_type(8))) short;
using f32x4   = __attribute__((ext_vector_type(4))) float;
using ushort8 = __attribute__((ext_vector_type(8))) unsigned short;

typedef const __attribute__((address_space(1))) void* gptr_t;
typedef __attribute__((address_space(3))) void* lptr_t;

static __device__ __forceinline__ unsigned short f2bf(float f) {
    uint32_t u = __builtin_bit_cast(uint32_t, f);
    uint32_t r = u + 0x7fffu + ((u >> 16) & 1u);   // RNE
    return (unsigned short)(r >> 16);
}

// Merged converter: one wave per row across BOTH x and centers.
// Converts f32 row -> bf16 row, emits exact-f32 sum of squares.
__global__ void convert_all(const float* __restrict__ x,
                            const float* __restrict__ c,
                            unsigned short* __restrict__ xb,
                            unsigned short* __restrict__ cb,
                            float* __restrict__ xsq,
                            float* __restrict__ csq) {
    const int wave = threadIdx.x >> 6;                 // 0..3
    const int lane = threadIdx.x & 63;
    const int row  = blockIdx.x * 4 + wave;            // global row id

    const float* src;
    unsigned short* dst;
    float* sq;
    int r;
    if (row < BATCH) { src = x; dst = xb; sq = xsq; r = row; }
    else             { src = c; dst = cb; sq = csq; r = row - BATCH; }

    const float* rp = src + (size_t)r * IN_F + lane * 8;
    float4 a = *reinterpret_cast<const float4*>(rp);
    float4 b = *reinterpret_cast<const float4*>(rp + 4);
    float ss = a.x*a.x + a.y*a.y + a.z*a.z + a.w*a.w
             + b.x*b.x + b.y*b.y + b.z*b.z + b.w*b.w;
    ushort8 o;
    o[0]=f2bf(a.x); o[1]=f2bf(a.y); o[2]=f2bf(a.z); o[3]=f2bf(a.w);
    o[4]=f2bf(b.x); o[5]=f2bf(b.y); o[6]=f2bf(b.z); o[7]=f2bf(b.w);
    *reinterpret_cast<ushort8*>(dst + (size_t)r * IN_F + lane * 8) = o;
    #pragma unroll
    for (int off = 32; off > 0; off >>= 1) ss += __shfl_down(ss, off);
    if (lane == 0) sq[r] = ss;
}

// 256x256-tile bf16 MFMA GEMM, 8-wave (2Mx4N), 4-phase-per-K-tile schedule
// (m201 template adapted): per phase {stage 1 half-tile || ds_read subtile ||
// 16 MFMA in setprio}, counted vmcnt(2) once per K-tile, XOR bank-swizzle on
// both stage-source and ds_read (rule #21). Fused RBF epilogue.
__launch_bounds__(512, 2)
__global__ void rbf_gemm(const unsigned short* __restrict__ xb,
                         const unsigned short* __restrict__ cb,
                         const float* __restrict__ xsq,
                         const float* __restrict__ csq,
                         const float* __restrict__ beta,
                         float* __restrict__ out) {
    // [buf][op A=0/B=1][half][128 rows * 64 cols] = 128 KiB
    __shared__ __align__(16) unsigned short lds[2][2][2][128 * 64];

    const int tid  = threadIdx.x;
    const int wid  = tid >> 6;               // 0..7
    const int lane = tid & 63;
    const int wr   = wid >> 2;               // 0..1  (M warps)
    const int wc   = wid & 3;                // 0..3  (N warps)

    // T1: XCD chunked swizzle (bijective: 512 % 8 == 0).
    const int bid = blockIdx.x;
    const int swz = (bid & 7) * 64 + (bid >> 3);
    const int ntn = N_CTR / BN;              // 8
    const int tm  = swz / ntn;               // 0..63
    const int tn  = swz % ntn;               // 0..7

    // stage-source swizzle: lane-static. LDS slot (row, l&7) receives data
    // chunk (l&7)^(row&7); row&7 == (l>>3)&7 within each 8-row group.
    const int csrc = (lane & 7) ^ ((lane >> 3) & 7);

    f32x4 acc[8][4] = {};

    auto stage_half = [&](int buf, int op, int h, int kt) {
        const unsigned short* src = (op == 0) ? xb : cb;
        const int tb = ((op == 0) ? tm : tn) * 256;
        #pragma unroll
        for (int j = 0; j < 2; ++j) {
            const int rl = wid * 16 + j * 8 + (lane >> 3);
            const unsigned short* g = src + (size_t)(tb + h * 128 + rl) * IN_F
                                      + kt * BK + csrc * 8;
            __builtin_amdgcn_global_load_lds(
                (gptr_t)g, (lptr_t)&lds[buf][op][h][(wid * 16 + j * 8) * 64],
                16, 0, 0);
        }
    };

    bf16x8 af[4][2];   // A quadrant, held across the two nh phases
    bf16x8 bfv[2][2];

    auto phase_compute = [&](int buf, int mh, int nh) {
        #pragma unroll
        for (int kk = 0; kk < 2; ++kk) {
            const int coff = (((kk * 4 + (lane >> 4)) ^ (lane & 7)) * 8);
            if (nh == 0) {
                #pragma unroll
                for (int i = 0; i < 4; ++i) {
                    const int rl = (mh * 4 + i) * 16 + (lane & 15);
                    af[i][kk] = *reinterpret_cast<const bf16x8*>(
                        &lds[buf][0][wr][rl * 64 + coff]);
                }
            }
            #pragma unroll
            for (int j = 0; j < 2; ++j) {
                const int rl = (wc & 1) * 64 + (nh * 2 + j) * 16 + (lane & 15);
                bfv[j][kk] = *reinterpret_cast<const bf16x8*>(
                    &lds[buf][1][wc >> 1][rl * 64 + coff]);
            }
        }
        __builtin_amdgcn_s_setprio(1);
        #pragma unroll
        for (int i = 0; i < 4; ++i)
            #pragma unroll
            for (int j = 0; j < 2; ++j)
                #pragma unroll
                for (int kk = 0; kk < 2; ++kk)
                    acc[mh * 4 + i][nh * 2 + j] =
                        __builtin_amdgcn_mfma_f32_16x16x32_bf16(
                            af[i][kk], bfv[j][kk], acc[mh * 4 + i][nh * 2 + j],
                            0, 0, 0);
        __builtin_amdgcn_s_setprio(0);
    };

    // ---- prologue: stage K-tile 0 (4 half-tiles) into buf 0 ----
    #pragma unroll
    for (int p = 0; p < 4; ++p) stage_half(0, p >> 1, p & 1, 0);

    // ---- main loop ----
    #pragma unroll
    for (int t = 0; t < NT; ++t) {
        const int cur = t & 1;
        const int nxt = cur ^ 1;
        const int ktn = (t + 1 < NT) ? t + 1 : NT - 1;  // last iter: harmless refetch
        #pragma unroll
        for (int p = 0; p < 4; ++p) {
            stage_half(nxt, p >> 1, p & 1, ktn);
            if (p == 0)
                asm volatile("s_waitcnt vmcnt(2)" ::: "memory");  // K-tile t landed,
                                                                  // 2 loads in flight
            asm volatile("s_barrier" ::: "memory");     // staged data visible to all
            __builtin_amdgcn_sched_barrier(0);
            phase_compute(cur, p >> 1, p & 1);
            __builtin_amdgcn_sched_barrier(0);
            asm volatile("s_barrier" ::: "memory");     // readers done before next
                                                        // iter's overwrite
        }
    }
    asm volatile("s_waitcnt vmcnt(0)" ::: "memory");    // drain tail refetch

    // ---- epilogue: out = exp(-beta * (xsq + csq - 2*cross)) ----
    const int row0 = tm * 256 + wr * 128;
    const int col0 = tn * 256 + wc * 64;
    #pragma unroll
    for (int n = 0; n < 4; ++n) {
        const int col = col0 + n * 16 + (lane & 15);
        const float bt = beta[col];
        const float cs = csq[col];
        #pragma unroll
        for (int m = 0; m < 8; ++m) {
            #pragma unroll
            for (int j = 0; j < 4; ++j) {
                const int row = row0 + m * 16 + (lane >> 4) * 4 + j;
                const float d = xsq[row] + cs - 2.0f * acc[m][n][j];
                out[(size_t)row * N_CTR + col] = __expf(-bt * d);
            }
        }
    }
}

// Fallback (ws too small): correct f32 path, LDS-staged x row.
__global__ void rbf_naive(const float* __restrict__ x,
                          const float* __restrict__ c,
                          const float* __restrict__ beta,
                          float* __restrict__ out) {
    __shared__ float xs[IN_F];
    const int row = blockIdx.x;
    const int col = blockIdx.y * 128 + threadIdx.x;
    for (int i = threadIdx.x; i < IN_F; i += 128)
        xs[i] = x[(size_t)row * IN_F + i];
    __syncthreads();
    const float* cp = c + (size_t)col * IN_F;
    float d = 0.f;
    #pragma unroll 4
    for (int k = 0; k < IN_F; k += 4) {
        float4 cv = *reinterpret_cast<const float4*>(cp + k);
        float t0 = xs[k + 0] - cv.x;
        float t1 = xs[k + 1] - cv.y;
        float t2 = xs[k + 2] - cv.z;
        float t3 = xs[k + 3] - cv.w;
        d += t0 * t0 + t1 * t1 + t2 * t2 + t3 * t3;
    }
    out[(size_t)row * N_CTR + col] = __expf(-beta[col] * d);
}

extern "C" void kernel_launch(void* const* d_in, const int* in_sizes, int n_in,
                              void* d_out, int out_size, void* d_ws, size_t ws_size,
                              hipStream_t stream) {
    const float* x    = (const float*)d_in[0];
    const float* c    = (const float*)d_in[1];
    const float* beta = (const float*)d_in[2];
    float* out        = (float*)d_out;

    const size_t need = (size_t)BATCH * IN_F * 2 + (size_t)N_CTR * IN_F * 2
                      + (size_t)BATCH * 4 + (size_t)N_CTR * 4;
    if (ws_size >= need) {
        unsigned short* xbuf = (unsigned short*)d_ws;
        unsigned short* cbuf = xbuf + (size_t)BATCH * IN_F;
        float* xsq = (float*)(cbuf + (size_t)N_CTR * IN_F);
        float* csq = xsq + BATCH;
        convert_all<<<(BATCH + N_CTR) / 4, 256, 0, stream>>>(x, c, xbuf, cbuf, xsq, csq);
        rbf_gemm<<<(BATCH / BM) * (N_CTR / BN), 512, 0, stream>>>(
            xbuf, cbuf, xsq, csq, beta, out);
    } else {
        rbf_naive<<<dim3(BATCH, N_CTR / 128), 128, 0, stream>>>(x, c, beta, out);
    }
}